// Round 1
// baseline (551.316 us; speedup 1.0000x reference)
//
#include <hip/hip_runtime.h>
#include <math.h>

// Monotonic order-preserving float->uint key for atomicMax-based float max.
__device__ __forceinline__ unsigned int float_key(float f) {
    unsigned int b = __float_as_uint(f);
    return (b & 0x80000000u) ? ~b : (b | 0x80000000u);
}

__global__ void init_kernel(unsigned int* key) {
    // d_out[0] is re-poisoned to 0xAA before every launch; key 0 is the
    // minimum possible key (acts as -inf identity for atomicMax).
    *key = 0u;
}

__global__ void finalize_kernel(float* out) {
    unsigned int k = ((unsigned int*)out)[0];
    unsigned int b = (k & 0x80000000u) ? (k ^ 0x80000000u) : ~k;
    out[0] = __uint_as_float(b);
}

// One block per row. 9 waves/block, wave w handles array w (w==8 -> mimic).
// Per wave: streaming float4 scan of its row computing top-2, target value,
// and (waves 0..7 only, for max_preds) running max. Wave reduce via shfl_xor,
// one barrier, thread 0 does the 9-way softmax + one keyed atomicMax.
__global__ __launch_bounds__(576) void margin_kernel(
    const float* __restrict__ o0, const float* __restrict__ o1,
    const float* __restrict__ o2, const float* __restrict__ o3,
    const float* __restrict__ o4, const float* __restrict__ o5,
    const float* __restrict__ o6, const float* __restrict__ o7,
    const float* __restrict__ o8,
    const int* __restrict__ targets,
    float* __restrict__ out, int C)
{
    __shared__ float s_margin[9];
    __shared__ float s_gmax[9];

    const int row  = blockIdx.x;
    const int wave = threadIdx.x >> 6;   // 0..8
    const int lane = threadIdx.x & 63;

    const float* ptrs[9] = {o0, o1, o2, o3, o4, o5, o6, o7, o8};
    const float* x = ptrs[wave] + (size_t)row * C;
    const int c = targets[row];

    float m1 = -INFINITY, m2 = -INFINITY;   // running top-2
    float tval = -INFINITY;                 // x[c] (only owner lane sets it)
    float gm = -INFINITY;                   // running max for max_preds

    const int nf4 = C >> 2;                 // 250 for C=1000
    const float4* x4 = (const float4*)x;
    const int cf4 = c >> 2, cs = c & 3;

    #pragma unroll 4
    for (int f4 = lane; f4 < nf4; f4 += 64) {
        float4 v = x4[f4];
        // branchless top-2 update (duplicate-max safe: ties give m1==m2)
        m2 = fmaxf(m2, fminf(m1, v.x)); m1 = fmaxf(m1, v.x);
        m2 = fmaxf(m2, fminf(m1, v.y)); m1 = fmaxf(m1, v.y);
        m2 = fmaxf(m2, fminf(m1, v.z)); m1 = fmaxf(m1, v.z);
        m2 = fmaxf(m2, fminf(m1, v.w)); m1 = fmaxf(m1, v.w);
        gm = fmaxf(gm, fmaxf(fmaxf(v.x, v.y), fmaxf(v.z, v.w)));
        if (f4 == cf4)
            tval = (cs == 0) ? v.x : (cs == 1) ? v.y : (cs == 2) ? v.z : v.w;
    }
    // scalar tail for C % 4 != 0 (no-op at C=1000)
    for (int idx = (nf4 << 2) + lane; idx < C; idx += 64) {
        float v = x[idx];
        m2 = fmaxf(m2, fminf(m1, v)); m1 = fmaxf(m1, v);
        gm = fmaxf(gm, v);
        if (idx == c) tval = v;
    }

    // wave-level butterfly reduction (no LDS, no barrier)
    #pragma unroll
    for (int off = 32; off > 0; off >>= 1) {
        float om1 = __shfl_xor(m1, off);
        float om2 = __shfl_xor(m2, off);
        m2 = fmaxf(fmaxf(m2, om2), fminf(m1, om1));   // 2nd of union
        m1 = fmaxf(m1, om1);
        gm = fmaxf(gm, __shfl_xor(gm, off));
        tval = fmaxf(tval, __shfl_xor(tval, off));    // only owner is > -inf
    }

    if (lane == 0) {
        s_margin[wave] = (tval == m1) ? (m1 - m2) : 0.0f;
        s_gmax[wave] = gm;
    }
    __syncthreads();

    if (threadIdx.x == 0) {
        // softmax(margins / 2) over the 9 models
        float mm = s_margin[0];
        #pragma unroll
        for (int k = 1; k < 9; ++k) mm = fmaxf(mm, s_margin[k]);
        float e[9], sum = 0.0f;
        #pragma unroll
        for (int k = 0; k < 9; ++k) {
            e[k] = expf((s_margin[k] - mm) * 0.5f);
            sum += e[k];
        }
        float inv = 1.0f / sum;
        float* orow = out + 1 + (size_t)row * 9;
        #pragma unroll
        for (int k = 0; k < 9; ++k) orow[k] = e[k] * inv;

        // max_preds over outputs1..8 only (exclude mimic, wave 8)
        float bg = s_gmax[0];
        #pragma unroll
        for (int k = 1; k < 8; ++k) bg = fmaxf(bg, s_gmax[k]);
        atomicMax((unsigned int*)out, float_key(bg));
    }
}

extern "C" void kernel_launch(void* const* d_in, const int* in_sizes, int n_in,
                              void* d_out, int out_size, void* d_ws, size_t ws_size,
                              hipStream_t stream) {
    const float* o0 = (const float*)d_in[0];
    const float* o1 = (const float*)d_in[1];
    const float* o2 = (const float*)d_in[2];
    const float* o3 = (const float*)d_in[3];
    const float* o4 = (const float*)d_in[4];
    const float* o5 = (const float*)d_in[5];
    const float* o6 = (const float*)d_in[6];
    const float* o7 = (const float*)d_in[7];
    const float* o8 = (const float*)d_in[8];   // mimic
    const int* targets = (const int*)d_in[9];
    const int N = in_sizes[9];                 // 16384
    const int C = in_sizes[0] / N;             // 1000
    float* out = (float*)d_out;                // [0]=max_preds, [1..]=out_threshold [N,9]

    init_kernel<<<1, 1, 0, stream>>>((unsigned int*)out);
    margin_kernel<<<dim3(N), dim3(576), 0, stream>>>(
        o0, o1, o2, o3, o4, o5, o6, o7, o8, targets, out, C);
    finalize_kernel<<<1, 1, 0, stream>>>(out);
}

// Round 2
// 492.578 us; speedup vs baseline: 1.1192x; 1.1192x over previous
//
#include <hip/hip_runtime.h>
#include <math.h>

#define GRID  1024   // blocks
#define BLOCK 256    // 4 waves/block -> 4096 waves; 16384 rows -> 4 rows/wave

// One wave per row; the wave scans all 9 arrays (fully unrolled -> no dynamic
// pointer indexing, no scratch). Per 64-lane chunk, 9 independent float4 loads
// sharing one voffset (9 SGPR bases). Branchless in-lane top-2, then a 6-round
// butterfly merge per array. Array max == reduced m1, so max_preds is free.
// No atomics: per-block partial max -> d_ws, reduced by a finalize kernel.
__global__ __launch_bounds__(BLOCK) void margin_kernel(
    const float* __restrict__ o0, const float* __restrict__ o1,
    const float* __restrict__ o2, const float* __restrict__ o3,
    const float* __restrict__ o4, const float* __restrict__ o5,
    const float* __restrict__ o6, const float* __restrict__ o7,
    const float* __restrict__ o8,
    const int* __restrict__ targets,
    float* __restrict__ out, float* __restrict__ block_max,
    int N, int C)
{
    __shared__ float s_gm[BLOCK / 64];

    const int lane   = threadIdx.x & 63;
    const int wib    = threadIdx.x >> 6;
    const int gwave  = blockIdx.x * (BLOCK / 64) + wib;
    const int nwaves = GRID * (BLOCK / 64);
    const int nf4    = C >> 2;

    float gm = -INFINITY;   // running max over arrays 0..7 (wave-uniform at end)

    for (int row = gwave; row < N; row += nwaves) {
        const int c = targets[row];
        const unsigned rowoff = (unsigned)row * (unsigned)C;

        // target values: uniform broadcast loads, issued early (latency hidden
        // under the main-loop loads)
        float tv[9];
        tv[0] = o0[rowoff + c]; tv[1] = o1[rowoff + c]; tv[2] = o2[rowoff + c];
        tv[3] = o3[rowoff + c]; tv[4] = o4[rowoff + c]; tv[5] = o5[rowoff + c];
        tv[6] = o6[rowoff + c]; tv[7] = o7[rowoff + c]; tv[8] = o8[rowoff + c];

        float m1[9], m2[9];
        #pragma unroll
        for (int k = 0; k < 9; ++k) { m1[k] = -INFINITY; m2[k] = -INFINITY; }

        const float4* p[9] = {
            (const float4*)(o0 + rowoff), (const float4*)(o1 + rowoff),
            (const float4*)(o2 + rowoff), (const float4*)(o3 + rowoff),
            (const float4*)(o4 + rowoff), (const float4*)(o5 + rowoff),
            (const float4*)(o6 + rowoff), (const float4*)(o7 + rowoff),
            (const float4*)(o8 + rowoff) };

        for (int f4 = lane; f4 < nf4; f4 += 64) {
            float4 v[9];
            #pragma unroll
            for (int k = 0; k < 9; ++k) v[k] = p[k][f4];   // 9 indep loads, shared voffset
            #pragma unroll
            for (int k = 0; k < 9; ++k) {
                m2[k] = fmaxf(m2[k], fminf(m1[k], v[k].x)); m1[k] = fmaxf(m1[k], v[k].x);
                m2[k] = fmaxf(m2[k], fminf(m1[k], v[k].y)); m1[k] = fmaxf(m1[k], v[k].y);
                m2[k] = fmaxf(m2[k], fminf(m1[k], v[k].z)); m1[k] = fmaxf(m1[k], v[k].z);
                m2[k] = fmaxf(m2[k], fminf(m1[k], v[k].w)); m1[k] = fmaxf(m1[k], v[k].w);
            }
        }
        // scalar tail (no-op for C % 4 == 0)
        for (int idx = (nf4 << 2) + lane; idx < C; idx += 64) {
            #pragma unroll
            for (int k = 0; k < 9; ++k) {
                float v = p[k >= 0 ? k : 0][0].x; // unreachable placeholder guard
                (void)v;
            }
        }
        if (C & 3) {  // generic tail, kept off the hot path
            for (int idx = (nf4 << 2) + lane; idx < C; idx += 64) {
                const float* b[9] = {o0,o1,o2,o3,o4,o5,o6,o7,o8};
                #pragma unroll
                for (int k = 0; k < 9; ++k) {
                    float v = b[k][rowoff + idx];
                    m2[k] = fmaxf(m2[k], fminf(m1[k], v)); m1[k] = fmaxf(m1[k], v);
                }
            }
        }

        // butterfly top-2 merge across 64 lanes, all 9 arrays jointly
        #pragma unroll
        for (int off = 32; off > 0; off >>= 1) {
            #pragma unroll
            for (int k = 0; k < 9; ++k) {
                float a1 = __shfl_xor(m1[k], off);
                float a2 = __shfl_xor(m2[k], off);
                m2[k] = fmaxf(fmaxf(m2[k], a2), fminf(m1[k], a1));
                m1[k] = fmaxf(m1[k], a1);
            }
        }

        float margin[9];
        #pragma unroll
        for (int k = 0; k < 9; ++k)
            margin[k] = (tv[k] == m1[k]) ? (m1[k] - m2[k]) : 0.0f;

        #pragma unroll
        for (int k = 0; k < 8; ++k) gm = fmaxf(gm, m1[k]);   // mimic excluded

        // softmax(margins / 2): wave-uniform values, computed in all lanes
        float mm = margin[0];
        #pragma unroll
        for (int k = 1; k < 9; ++k) mm = fmaxf(mm, margin[k]);
        float sum = 0.0f;
        #pragma unroll
        for (int k = 0; k < 9; ++k) sum += expf((margin[k] - mm) * 0.5f);
        float inv = 1.0f / sum;

        float msel = margin[0];
        #pragma unroll
        for (int k = 1; k < 9; ++k) msel = (lane == k) ? margin[k] : msel;
        if (lane < 9)
            out[1 + (size_t)row * 9 + lane] = expf((msel - mm) * 0.5f) * inv;
    }

    // one plain store per block (no atomics)
    if (lane == 0) s_gm[wib] = gm;
    __syncthreads();
    if (threadIdx.x == 0) {
        float bg = s_gm[0];
        #pragma unroll
        for (int w = 1; w < BLOCK / 64; ++w) bg = fmaxf(bg, s_gm[w]);
        block_max[blockIdx.x] = bg;
    }
}

__global__ __launch_bounds__(256) void finalize_kernel(
    const float* __restrict__ block_max, float* __restrict__ out, int n)
{
    __shared__ float s[4];
    const int lane = threadIdx.x & 63;
    float v = -INFINITY;
    for (int i = threadIdx.x; i < n; i += 256) v = fmaxf(v, block_max[i]);
    #pragma unroll
    for (int off = 32; off > 0; off >>= 1) v = fmaxf(v, __shfl_xor(v, off));
    if (lane == 0) s[threadIdx.x >> 6] = v;
    __syncthreads();
    if (threadIdx.x == 0)
        out[0] = fmaxf(fmaxf(s[0], s[1]), fmaxf(s[2], s[3]));
}

extern "C" void kernel_launch(void* const* d_in, const int* in_sizes, int n_in,
                              void* d_out, int out_size, void* d_ws, size_t ws_size,
                              hipStream_t stream) {
    const float* o0 = (const float*)d_in[0];
    const float* o1 = (const float*)d_in[1];
    const float* o2 = (const float*)d_in[2];
    const float* o3 = (const float*)d_in[3];
    const float* o4 = (const float*)d_in[4];
    const float* o5 = (const float*)d_in[5];
    const float* o6 = (const float*)d_in[6];
    const float* o7 = (const float*)d_in[7];
    const float* o8 = (const float*)d_in[8];   // mimic
    const int* targets = (const int*)d_in[9];
    const int N = in_sizes[9];                 // 16384
    const int C = in_sizes[0] / N;             // 1000
    float* out = (float*)d_out;                // [0]=max_preds, [1..]=out_threshold [N,9]
    float* block_max = (float*)d_ws;           // GRID floats of scratch

    margin_kernel<<<dim3(GRID), dim3(BLOCK), 0, stream>>>(
        o0, o1, o2, o3, o4, o5, o6, o7, o8, targets, out, block_max, N, C);
    finalize_kernel<<<1, 256, 0, stream>>>(block_max, out, GRID);
}